// Round 1
// baseline (2897.450 us; speedup 1.0000x reference)
//
#include <hip/hip_runtime.h>
#include <hip/hip_bf16.h>

// Problem constants (from reference)
#define B_  64
#define T_  256
#define D_  768
#define NH_ 12
#define DH_ 64
#define C_  7

// ---------------------------------------------------------------------------
// Tiled f32 GEMM: C[M,N] = A[M,K] @ W[K,N] + bias[N], optional zero of t==0 rows
// BM=BN=64, BK=16, 256 threads, 4x4 micro-tile per thread.
// M=16384, N=768, K=768 -> all divisible, no bounds checks.
// ---------------------------------------------------------------------------
#define BM 64
#define BN 64
#define BK 16

__global__ __launch_bounds__(256) void gemm_bias_f32(
    const float* __restrict__ A, const float* __restrict__ W,
    const float* __restrict__ bias, float* __restrict__ C,
    int M, int N, int K, int zero_t0)
{
    __shared__ float As[BK][BM + 1];
    __shared__ float Bs[BK][BN + 1];

    const int bn = blockIdx.x;   // N tiles
    const int bm = blockIdx.y;   // M tiles
    const int tid = threadIdx.x;
    const int tx = tid & 15;     // 0..15 -> 4 cols each
    const int ty = tid >> 4;     // 0..15 -> 4 rows each

    const int row0 = bm * BM;
    const int col0 = bn * BN;

    float acc[4][4];
#pragma unroll
    for (int i = 0; i < 4; ++i)
#pragma unroll
        for (int j = 0; j < 4; ++j) acc[i][j] = 0.f;

    for (int k0 = 0; k0 < K; k0 += BK) {
        // Load A tile: 64x16, consecutive tid -> consecutive k (coalesced 64B runs)
#pragma unroll
        for (int i = tid; i < BM * BK; i += 256) {
            int m = i >> 4, kk = i & 15;
            As[kk][m] = A[(size_t)(row0 + m) * K + k0 + kk];
        }
        // Load W tile: 16x64, consecutive tid -> consecutive n (coalesced)
#pragma unroll
        for (int i = tid; i < BK * BN; i += 256) {
            int kk = i >> 6, n = i & 63;
            Bs[kk][n] = W[(size_t)(k0 + kk) * N + col0 + n];
        }
        __syncthreads();
#pragma unroll
        for (int kk = 0; kk < BK; ++kk) {
            float a[4], b[4];
#pragma unroll
            for (int i = 0; i < 4; ++i) a[i] = As[kk][ty * 4 + i];
#pragma unroll
            for (int j = 0; j < 4; ++j) b[j] = Bs[kk][tx * 4 + j];
#pragma unroll
            for (int i = 0; i < 4; ++i)
#pragma unroll
                for (int j = 0; j < 4; ++j) acc[i][j] += a[i] * b[j];
        }
        __syncthreads();
    }

#pragma unroll
    for (int i = 0; i < 4; ++i) {
        int row = row0 + ty * 4 + i;
        int t = row & (T_ - 1);            // row % T (T=256 power of 2)
        bool zero = (zero_t0 != 0) && (t == 0);
#pragma unroll
        for (int j = 0; j < 4; ++j) {
            int col = col0 + tx * 4 + j;
            float val = zero ? 0.f : (acc[i][j] + bias[col]);
            C[(size_t)row * N + col] = val;
        }
    }
}

// ---------------------------------------------------------------------------
// Attention: one 64-lane wave per (b, h, t) query row. Online softmax over
// kmax = min(t, num_turns[b]) keys. lane = d within the head (DH=64).
// ---------------------------------------------------------------------------
__global__ __launch_bounds__(64) void attn_kernel(
    const float* __restrict__ q, const float* __restrict__ k,
    const float* __restrict__ v, const int* __restrict__ num_turns,
    float* __restrict__ ctx)
{
    const int idx = blockIdx.x;          // ((b*NH + h) * T + t)
    const int t = idx & (T_ - 1);
    const int bh = idx >> 8;             // T = 256
    const int h = bh % NH_;
    const int b = bh / NH_;
    const int lane = threadIdx.x;

    float* ctx_ptr = ctx + ((size_t)(b * T_ + t)) * D_ + h * DH_ + lane;

    const int nt = num_turns[b];
    const int kmax = min(t, nt);
    if (kmax <= 0) { *ctx_ptr = 0.f; return; }

    const float qd = q[((size_t)(b * T_ + t)) * D_ + h * DH_ + lane] * 0.125f;
    const float* kbase = k + ((size_t)b * T_) * D_ + h * DH_ + lane;
    const float* vbase = v + ((size_t)b * T_) * D_ + h * DH_ + lane;

    float m = -1e30f, l = 0.f, acc = 0.f;
    for (int kk = 0; kk < kmax; ++kk) {
        float p = qd * kbase[(size_t)kk * D_];
#pragma unroll
        for (int off = 32; off; off >>= 1) p += __shfl_xor(p, off, 64);
        float mn = fmaxf(m, p);
        float corr = __expf(m - mn);
        float w = __expf(p - mn);
        l = l * corr + w;
        acc = acc * corr + w * vbase[(size_t)kk * D_];
        m = mn;
    }
    *ctx_ptr = acc / l;
}

// ---------------------------------------------------------------------------
// Logits: one 256-thread block per (b,t) row.
// all_logits[row] = [H_row, c_row] @ Wc + bc ; also final_logits gather.
// ---------------------------------------------------------------------------
__global__ __launch_bounds__(256) void logits_kernel(
    const float* __restrict__ H, const float* __restrict__ c,
    const float* __restrict__ Wc, const float* __restrict__ bc,
    const int* __restrict__ num_turns, float* __restrict__ out)
{
    __shared__ float sWc[2 * D_ * C_];   // 1536*7 floats = 43008 B
    __shared__ float sred[4 * C_];

    const int row = blockIdx.x;          // b*T + t
    const int tid = threadIdx.x;

    for (int i = tid; i < 2 * D_ * C_; i += 256) sWc[i] = Wc[i];
    __syncthreads();

    const float* hrow = H + (size_t)row * D_;
    const float* crow = c + (size_t)row * D_;

    float accj[C_];
#pragma unroll
    for (int j = 0; j < C_; ++j) accj[j] = 0.f;

    for (int kk = tid; kk < D_; kk += 256) {
        float z = hrow[kk];
        const float* w = &sWc[kk * C_];
#pragma unroll
        for (int j = 0; j < C_; ++j) accj[j] += z * w[j];
    }
    for (int kk = tid; kk < D_; kk += 256) {
        float z = crow[kk];
        const float* w = &sWc[(D_ + kk) * C_];
#pragma unroll
        for (int j = 0; j < C_; ++j) accj[j] += z * w[j];
    }

    // wave reduce (64-wide), then cross-wave via LDS
#pragma unroll
    for (int off = 32; off; off >>= 1)
#pragma unroll
        for (int j = 0; j < C_; ++j) accj[j] += __shfl_xor(accj[j], off, 64);

    const int wave = tid >> 6;
    const int lane = tid & 63;
    if (lane == 0) {
#pragma unroll
        for (int j = 0; j < C_; ++j) sred[wave * C_ + j] = accj[j];
    }
    __syncthreads();

    if (tid < C_) {
        float tot = sred[tid] + sred[C_ + tid] + sred[2 * C_ + tid] + sred[3 * C_ + tid]
                  + bc[tid];
        out[(size_t)row * C_ + tid] = tot;
        int b = row >> 8;               // row / T
        int t = row & (T_ - 1);
        if (t == num_turns[b] - 1) {
            out[(size_t)B_ * T_ * C_ + (size_t)b * C_ + tid] = tot;
        }
    }
}

// ---------------------------------------------------------------------------
extern "C" void kernel_launch(void* const* d_in, const int* in_sizes, int n_in,
                              void* d_out, int out_size, void* d_ws, size_t ws_size,
                              hipStream_t stream)
{
    const float* H  = (const float*)d_in[0];
    const float* Wq = (const float*)d_in[1];
    const float* bq = (const float*)d_in[2];
    const float* Wk = (const float*)d_in[3];
    const float* bk = (const float*)d_in[4];
    const float* Wv = (const float*)d_in[5];
    const float* bv = (const float*)d_in[6];
    const float* Wo = (const float*)d_in[7];
    const float* bo = (const float*)d_in[8];
    const float* Wc = (const float*)d_in[9];
    const float* bc = (const float*)d_in[10];
    const int* num_turns = (const int*)d_in[11];
    float* out = (float*)d_out;

    const int M = B_ * T_;        // 16384
    const size_t per = (size_t)M * D_;   // 12,582,912 floats

    float* ws = (float*)d_ws;
    float* qb   = ws;
    float* kb   = ws + per;
    float* vb   = ws + 2 * per;
    float* ctxb = ws + 3 * per;
    float* cb   = qb;             // q is dead after attention; reuse for c

    dim3 gGrid(D_ / BN, M / BM);  // (12, 256)
    dim3 gBlock(256);

    // q, k, v projections
    gemm_bias_f32<<<gGrid, gBlock, 0, stream>>>(H, Wq, bq, qb, M, D_, D_, 0);
    gemm_bias_f32<<<gGrid, gBlock, 0, stream>>>(H, Wk, bk, kb, M, D_, D_, 0);
    gemm_bias_f32<<<gGrid, gBlock, 0, stream>>>(H, Wv, bv, vb, M, D_, D_, 0);

    // attention: one wave per (b,h,t)
    attn_kernel<<<B_ * NH_ * T_, 64, 0, stream>>>(qb, kb, vb, num_turns, ctxb);

    // out projection with t==0 row zeroing
    gemm_bias_f32<<<gGrid, gBlock, 0, stream>>>(ctxb, Wo, bo, cb, M, D_, D_, 1);

    // fused concat + logits + final gather
    logits_kernel<<<M, 256, 0, stream>>>(H, cb, Wc, bc, num_turns, out);
}

// Round 2
// 1943.073 us; speedup vs baseline: 1.4912x; 1.4912x over previous
//
#include <hip/hip_runtime.h>
#include <hip/hip_bf16.h>

#define B_  64
#define T_  256
#define D_  768
#define NH_ 12
#define DH_ 64
#define C_  7

using f32x4  = __attribute__((ext_vector_type(4))) float;
using bf16x8 = __attribute__((ext_vector_type(8))) __bf16;
using u16x8  = __attribute__((ext_vector_type(8))) unsigned short;

static __device__ inline unsigned short f2bf(float f) {
    union { float f; unsigned u; } c; c.f = f;
    unsigned u = c.u;
    return (unsigned short)((u + 0x7fffu + ((u >> 16) & 1u)) >> 16);
}

static __device__ inline bf16x8 load_frag_f32(const float* p) {
    const float4 f0 = *(const float4*)p;
    const float4 f1 = *(const float4*)(p + 4);
    u16x8 u;
    u[0] = f2bf(f0.x); u[1] = f2bf(f0.y); u[2] = f2bf(f0.z); u[3] = f2bf(f0.w);
    u[4] = f2bf(f1.x); u[5] = f2bf(f1.y); u[6] = f2bf(f1.z); u[7] = f2bf(f1.w);
    return __builtin_bit_cast(bf16x8, u);
}

// ---------------------------------------------------------------------------
#define BM 64
#define BN 64
#define BK 16

__global__ __launch_bounds__(256) void gemm_bias_f32(
    const float* __restrict__ A, const float* __restrict__ W,
    const float* __restrict__ bias, float* __restrict__ C,
    int M, int N, int K, int zero_t0)
{
    __shared__ float As[BK][BM + 1];
    __shared__ float Bs[BK][BN + 1];

    const int bn = blockIdx.x;
    const int bm = blockIdx.y;
    const int tid = threadIdx.x;
    const int tx = tid & 15;
    const int ty = tid >> 4;

    const int row0 = bm * BM;
    const int col0 = bn * BN;

    float acc[4][4];
#pragma unroll
    for (int i = 0; i < 4; ++i)
#pragma unroll
        for (int j = 0; j < 4; ++j) acc[i][j] = 0.f;

    for (int k0 = 0; k0 < K; k0 += BK) {
#pragma unroll
        for (int i = tid; i < BM * BK; i += 256) {
            int m = i >> 4, kk = i & 15;
            As[kk][m] = A[(size_t)(row0 + m) * K + k0 + kk];
        }
#pragma unroll
        for (int i = tid; i < BK * BN; i += 256) {
            int kk = i >> 6, n = i & 63;
            Bs[kk][n] = W[(size_t)(k0 + kk) * N + col0 + n];
        }
        __syncthreads();
#pragma unroll
        for (int kk = 0; kk < BK; ++kk) {
            float a[4], b[4];
#pragma unroll
            for (int i = 0; i < 4; ++i) a[i] = As[kk][ty * 4 + i];
#pragma unroll
            for (int j = 0; j < 4; ++j) b[j] = Bs[kk][tx * 4 + j];
#pragma unroll
            for (int i = 0; i < 4; ++i)
#pragma unroll
                for (int j = 0; j < 4; ++j) acc[i][j] += a[i] * b[j];
        }
        __syncthreads();
    }

#pragma unroll
    for (int i = 0; i < 4; ++i) {
        int row = row0 + ty * 4 + i;
        int t = row & (T_ - 1);
        bool zero = (zero_t0 != 0) && (t == 0);
#pragma unroll
        for (int j = 0; j < 4; ++j) {
            int col = col0 + tx * 4 + j;
            float val = zero ? 0.f : (acc[i][j] + bias[col]);
            C[(size_t)row * N + col] = val;
        }
    }
}

// ---------------------------------------------------------------------------
// Fused MFMA flash attention. Grid (B*NH, T/64); 4 waves; wave = 16-query
// m-block at m0 = qt*64 + wave*16. See round journal for layout derivation.
// ---------------------------------------------------------------------------
__global__ __launch_bounds__(256) void attn_fused(
    const float* __restrict__ q, const float* __restrict__ k,
    const float* __restrict__ v, const int* __restrict__ num_turns,
    float* __restrict__ ctx)
{
    __shared__ unsigned short Plds[4][16 * 264];

    const int bh = blockIdx.x;
    const int b = bh / NH_;
    const int h = bh - b * NH_;
    const int qt = blockIdx.y;
    const int tid = threadIdx.x;
    const int wave = tid >> 6;
    const int lane = tid & 63;
    const int hi = lane >> 4;
    const int lo = lane & 15;

    const int m0 = qt * 64 + wave * 16;
    const int nt = num_turns[b];

    const int kmax = min(m0 + 14, nt - 1);
    const int n0hi = (kmax >> 4) | 1;
    const int nks  = (kmax >> 5) + 1;

    bf16x8 aq[2];
#pragma unroll
    for (int ks = 0; ks < 2; ++ks) {
        const float* p = q + ((size_t)(b * T_ + m0 + lo)) * D_ + h * DH_ + ks * 32 + hi * 8;
        aq[ks] = load_frag_f32(p);
    }

    f32x4 s[16];
#pragma unroll
    for (int n0 = 0; n0 < 16; ++n0) {
        s[n0][0] = 0.f; s[n0][1] = 0.f; s[n0][2] = 0.f; s[n0][3] = 0.f;
    }
#pragma unroll
    for (int n0 = 0; n0 < 16; ++n0) {
        if (n0 <= n0hi) {
#pragma unroll
            for (int ks = 0; ks < 2; ++ks) {
                const float* p = k + ((size_t)(b * T_ + n0 * 16 + lo)) * D_ + h * DH_ + ks * 32 + hi * 8;
                bf16x8 bk = load_frag_f32(p);
                s[n0] = __builtin_amdgcn_mfma_f32_16x16x32_bf16(aq[ks], bk, s[n0], 0, 0, 0);
            }
        }
    }

#pragma unroll
    for (int r = 0; r < 4; ++r) {
        const int qrow = m0 + hi * 4 + r;
        float mr = -1e30f;
#pragma unroll
        for (int n0 = 0; n0 < 16; ++n0) {
            if (n0 <= n0hi) {
                int key = n0 * 16 + lo;
                bool valid = (key < qrow) && (key < nt);
                float se = valid ? s[n0][r] * 0.125f : -1e30f;
                s[n0][r] = se;
                mr = fmaxf(mr, se);
            }
        }
#pragma unroll
        for (int off = 1; off < 16; off <<= 1) mr = fmaxf(mr, __shfl_xor(mr, off, 64));

        float lr = 0.f;
#pragma unroll
        for (int n0 = 0; n0 < 16; ++n0) {
            if (n0 <= n0hi) {
                float se = s[n0][r];
                float pv = (se > -5e29f) ? __expf(se - mr) : 0.f;
                s[n0][r] = pv;
                lr += pv;
            }
        }
#pragma unroll
        for (int off = 1; off < 16; off <<= 1) lr += __shfl_xor(lr, off, 64);

        float inv = (lr > 0.f) ? (1.f / lr) : 0.f;
#pragma unroll
        for (int n0 = 0; n0 < 16; ++n0) {
            if (n0 <= n0hi) {
                Plds[wave][(hi * 4 + r) * 264 + n0 * 16 + lo] = f2bf(s[n0][r] * inv);
            }
        }
    }

    f32x4 o[4];
#pragma unroll
    for (int nd = 0; nd < 4; ++nd) { o[nd][0] = 0.f; o[nd][1] = 0.f; o[nd][2] = 0.f; o[nd][3] = 0.f; }

#pragma unroll
    for (int ks = 0; ks < 8; ++ks) {
        if (ks < nks) {
            const unsigned short* lp = &Plds[wave][lo * 264 + ks * 32 + hi * 8];
            bf16x8 ap = __builtin_bit_cast(bf16x8, *(const uint4*)lp);
#pragma unroll
            for (int nd = 0; nd < 4; ++nd) {
                const float* vp = v + ((size_t)(b * T_ + ks * 32 + hi * 8)) * D_ + h * DH_ + nd * 16 + lo;
                u16x8 bu;
#pragma unroll
                for (int j = 0; j < 8; ++j) bu[j] = f2bf(vp[(size_t)j * D_]);
                bf16x8 bv = __builtin_bit_cast(bf16x8, bu);
                o[nd] = __builtin_amdgcn_mfma_f32_16x16x32_bf16(ap, bv, o[nd], 0, 0, 0);
            }
        }
    }

#pragma unroll
    for (int nd = 0; nd < 4; ++nd) {
#pragma unroll
        for (int r = 0; r < 4; ++r) {
            ctx[((size_t)(b * T_ + m0 + hi * 4 + r)) * D_ + h * DH_ + nd * 16 + lo] = o[nd][r];
        }
    }
}

// ---------------------------------------------------------------------------
__global__ __launch_bounds__(256) void logits_kernel(
    const float* __restrict__ H, const float* __restrict__ c,
    const float* __restrict__ Wc, const float* __restrict__ bc,
    const int* __restrict__ num_turns, float* __restrict__ out)
{
    __shared__ float sWc[2 * D_ * C_];
    __shared__ float sred[4 * C_];

    const int row = blockIdx.x;
    const int tid = threadIdx.x;

    for (int i = tid; i < 2 * D_ * C_; i += 256) sWc[i] = Wc[i];
    __syncthreads();

    const float* hrow = H + (size_t)row * D_;
    const float* crow = c + (size_t)row * D_;

    float accj[C_];
#pragma unroll
    for (int j = 0; j < C_; ++j) accj[j] = 0.f;

    for (int kk = tid; kk < D_; kk += 256) {
        float z = hrow[kk];
        const float* w = &sWc[kk * C_];
#pragma unroll
        for (int j = 0; j < C_; ++j) accj[j] += z * w[j];
    }
    for (int kk = tid; kk < D_; kk += 256) {
        float z = crow[kk];
        const float* w = &sWc[(D_ + kk) * C_];
#pragma unroll
        for (int j = 0; j < C_; ++j) accj[j] += z * w[j];
    }

#pragma unroll
    for (int off = 32; off; off >>= 1)
#pragma unroll
        for (int j = 0; j < C_; ++j) accj[j] += __shfl_xor(accj[j], off, 64);

    const int wave = tid >> 6;
    const int lane = tid & 63;
    if (lane == 0) {
#pragma unroll
        for (int j = 0; j < C_; ++j) sred[wave * C_ + j] = accj[j];
    }
    __syncthreads();

    if (tid < C_) {
        float tot = sred[tid] + sred[C_ + tid] + sred[2 * C_ + tid] + sred[3 * C_ + tid]
                  + bc[tid];
        out[(size_t)row * C_ + tid] = tot;
        int b = row >> 8;
        int t = row & (T_ - 1);
        if (t == num_turns[b] - 1) {
            out[(size_t)B_ * T_ * C_ + (size_t)b * C_ + tid] = tot;
        }
    }
}

// ---------------------------------------------------------------------------
extern "C" void kernel_launch(void* const* d_in, const int* in_sizes, int n_in,
                              void* d_out, int out_size, void* d_ws, size_t ws_size,
                              hipStream_t stream)
{
    const float* H  = (const float*)d_in[0];
    const float* Wq = (const float*)d_in[1];
    const float* bq = (const float*)d_in[2];
    const float* Wk = (const float*)d_in[3];
    const float* bk = (const float*)d_in[4];
    const float* Wv = (const float*)d_in[5];
    const float* bv = (const float*)d_in[6];
    const float* Wo = (const float*)d_in[7];
    const float* bo = (const float*)d_in[8];
    const float* Wc = (const float*)d_in[9];
    const float* bc = (const float*)d_in[10];
    const int* num_turns = (const int*)d_in[11];
    float* out = (float*)d_out;

    const int M = B_ * T_;
    const size_t per = (size_t)M * D_;

    float* ws = (float*)d_ws;
    float* qb   = ws;
    float* kb   = ws + per;
    float* vb   = ws + 2 * per;
    float* ctxb = ws + 3 * per;
    float* cb   = qb;

    dim3 gGrid(D_ / BN, M / BM);
    dim3 gBlock(256);

    gemm_bias_f32<<<gGrid, gBlock, 0, stream>>>(H, Wq, bq, qb, M, D_, D_, 0);
    gemm_bias_f32<<<gGrid, gBlock, 0, stream>>>(H, Wk, bk, kb, M, D_, D_, 0);
    gemm_bias_f32<<<gGrid, gBlock, 0, stream>>>(H, Wv, bv, vb, M, D_, D_, 0);

    dim3 aGrid(B_ * NH_, T_ / 64);
    attn_fused<<<aGrid, 256, 0, stream>>>(qb, kb, vb, num_turns, ctxb);

    gemm_bias_f32<<<gGrid, gBlock, 0, stream>>>(ctxb, Wo, bo, cb, M, D_, D_, 1);

    logits_kernel<<<M, 256, 0, stream>>>(H, cb, Wc, bc, num_turns, out);
}

// Round 3
// 452.816 us; speedup vs baseline: 6.3987x; 4.2911x over previous
//
#include <hip/hip_runtime.h>
#include <hip/hip_bf16.h>

#define B_  64
#define T_  256
#define D_  768
#define NH_ 12
#define DH_ 64
#define C_  7
#define QS_ 2304            // qkv fused row stride (3*D)

using f32x4  = __attribute__((ext_vector_type(4))) float;
using bf16x8 = __attribute__((ext_vector_type(8))) __bf16;
using u16x8  = __attribute__((ext_vector_type(8))) unsigned short;

static __device__ inline unsigned short f2bf(float f) {
    union { float f; unsigned u; } c; c.f = f;
    unsigned u = c.u;
    return (unsigned short)((u + 0x7fffu + ((u >> 16) & 1u)) >> 16);
}

// async global->LDS, 16 bytes per lane (wave-uniform LDS base + lane*16)
#define ASYNC16(gp, lp) __builtin_amdgcn_global_load_lds(                      \
    (const __attribute__((address_space(1))) unsigned int*)(gp),               \
    (__attribute__((address_space(3))) unsigned int*)(lp), 16, 0, 0)

// ---------------------------------------------------------------------------
// f32 -> bf16 convert (n multiple of 8)
// ---------------------------------------------------------------------------
__global__ __launch_bounds__(256) void convert_f32_bf16(
    const float* __restrict__ in, unsigned short* __restrict__ out, int n)
{
    int i = (blockIdx.x * 256 + threadIdx.x) * 8;
    if (i < n) {
        float4 f0 = *(const float4*)(in + i);
        float4 f1 = *(const float4*)(in + i + 4);
        u16x8 u;
        u[0] = f2bf(f0.x); u[1] = f2bf(f0.y); u[2] = f2bf(f0.z); u[3] = f2bf(f0.w);
        u[4] = f2bf(f1.x); u[5] = f2bf(f1.y); u[6] = f2bf(f1.z); u[7] = f2bf(f1.w);
        *(uint4*)(out + i) = __builtin_bit_cast(uint4, u);
    }
}

// ---------------------------------------------------------------------------
// W [K,N] f32 -> Wt [N,K] bf16 (transpose), 32x32 LDS tiles, rows=cols=768
// ---------------------------------------------------------------------------
__global__ __launch_bounds__(256) void transpose_to_bf16(
    const float* __restrict__ W, unsigned short* __restrict__ Wt, int rows, int cols)
{
    __shared__ float tile[32][33];
    const int bx = blockIdx.x * 32;   // col tile (n)
    const int by = blockIdx.y * 32;   // row tile (k)
    const int tx = threadIdx.x & 31;
    const int ty = threadIdx.x >> 5;  // 0..7
#pragma unroll
    for (int i = ty; i < 32; i += 8)
        tile[i][tx] = W[(size_t)(by + i) * cols + bx + tx];
    __syncthreads();
#pragma unroll
    for (int i = ty; i < 32; i += 8)
        Wt[(size_t)(bx + i) * rows + by + tx] = f2bf(tile[tx][i]);
}

__global__ __launch_bounds__(256) void concat_bias3(
    const float* __restrict__ b0, const float* __restrict__ b1,
    const float* __restrict__ b2, float* __restrict__ out)
{
    int i = blockIdx.x * 256 + threadIdx.x;
    if (i < D_)          out[i] = b0[i];
    else if (i < 2 * D_) out[i] = b1[i - D_];
    else if (i < 3 * D_) out[i] = b2[i - 2 * D_];
}

// ---------------------------------------------------------------------------
// bf16 MFMA GEMM (m97 structure): C[M,N] = A[M,K] @ Bt[N,K]^T + bias
// 128x128 tile, BK=32, 4 waves (2x2, 64x64 each), global_load_lds width=16,
// ds_read_b128 fragments, 16x16x32 MFMA. flags: 1 = zero t==0 rows,
// 2 = bf16 output (else f32).
// ---------------------------------------------------------------------------
#define GBM 128
#define GBN 128
#define GBK 32

__global__ __launch_bounds__(256) void gemm_bf16_mfma(
    const unsigned short* __restrict__ A,   // [M,K] bf16
    const unsigned short* __restrict__ Bt,  // [N,K] bf16
    const float* __restrict__ bias,         // [N]
    void* __restrict__ Cout,
    int M, int N, int K, int flags)
{
    __shared__ unsigned short As[GBM * GBK];
    __shared__ unsigned short Bs[GBN * GBK];

    const int tid = threadIdx.x;
    const int wv  = tid >> 6;
    const int ln  = tid & 63;
    const int hi  = ln >> 4;
    const int lo  = ln & 15;

    const int row0 = blockIdx.y * GBM;
    const int col0 = blockIdx.x * GBN;
    const int wm = (wv & 1) * 64;
    const int wn = (wv >> 1) * 64;

    f32x4 acc[4][4] = {};

    // staging indices: chunk c, idx = c*256+tid in [0,512); 8 elems per idx
    const int r0a = (0 * 256 + tid) >> 2, kc0 = (0 * 256 + tid) & 3;
    const int r1a = (1 * 256 + tid) >> 2, kc1 = (1 * 256 + tid) & 3;

    for (int k0 = 0; k0 < K; k0 += GBK) {
        ASYNC16(A + (size_t)(row0 + r0a) * K + k0 + kc0 * 8, &As[(0 * 256 + wv * 64) * 8]);
        ASYNC16(A + (size_t)(row0 + r1a) * K + k0 + kc1 * 8, &As[(1 * 256 + wv * 64) * 8]);
        ASYNC16(Bt + (size_t)(col0 + r0a) * K + k0 + kc0 * 8, &Bs[(0 * 256 + wv * 64) * 8]);
        ASYNC16(Bt + (size_t)(col0 + r1a) * K + k0 + kc1 * 8, &Bs[(1 * 256 + wv * 64) * 8]);
        __syncthreads();

        bf16x8 af[4], bf[4];
#pragma unroll
        for (int i = 0; i < 4; ++i)
            af[i] = *(const bf16x8*)&As[(wm + i * 16 + lo) * GBK + hi * 8];
#pragma unroll
        for (int j = 0; j < 4; ++j)
            bf[j] = *(const bf16x8*)&Bs[(wn + j * 16 + lo) * GBK + hi * 8];
#pragma unroll
        for (int i = 0; i < 4; ++i)
#pragma unroll
            for (int j = 0; j < 4; ++j)
                acc[i][j] = __builtin_amdgcn_mfma_f32_16x16x32_bf16(af[i], bf[j], acc[i][j], 0, 0, 0);
        __syncthreads();
    }

    const bool zt  = (flags & 1) != 0;
    const bool obf = (flags & 2) != 0;
#pragma unroll
    for (int j = 0; j < 4; ++j) {
        const int col = col0 + wn + j * 16 + lo;
        const float bcol = bias[col];
#pragma unroll
        for (int i = 0; i < 4; ++i) {
#pragma unroll
            for (int r = 0; r < 4; ++r) {
                const int row = row0 + wm + i * 16 + hi * 4 + r;
                float val = acc[i][j][r] + bcol;
                if (zt && ((row & (T_ - 1)) == 0)) val = 0.f;
                if (obf) ((unsigned short*)Cout)[(size_t)row * N + col] = f2bf(val);
                else     ((float*)Cout)[(size_t)row * N + col] = val;
            }
        }
    }
}

// ---------------------------------------------------------------------------
// Fused MFMA flash attention over the packed bf16 qkv buffer [M, 2304].
// Grid (B*NH, T/64); 4 waves; wave owns 16-query m-block. ctx out: bf16 [M,768].
// ---------------------------------------------------------------------------
__global__ __launch_bounds__(256) void attn_fused(
    const unsigned short* __restrict__ qkv, const int* __restrict__ num_turns,
    unsigned short* __restrict__ ctx)
{
    __shared__ unsigned short Plds[4][16 * 264];

    const int bh = blockIdx.x;
    const int b = bh / NH_;
    const int h = bh - b * NH_;
    const int qt = blockIdx.y;
    const int tid = threadIdx.x;
    const int wave = tid >> 6;
    const int lane = tid & 63;
    const int hi = lane >> 4;
    const int lo = lane & 15;

    const int m0 = qt * 64 + wave * 16;
    const int nt = num_turns[b];

    const int kmax = min(m0 + 14, nt - 1);
    const int n0hi = (kmax >> 4) | 1;
    const int nks  = (kmax >> 5) + 1;

    const unsigned short* qb = qkv + (size_t)(b * T_) * QS_ + h * DH_;           // q
    const unsigned short* kb = qb + D_;                                          // k
    const unsigned short* vb = qb + 2 * D_;                                      // v

    bf16x8 aq[2];
#pragma unroll
    for (int ks = 0; ks < 2; ++ks)
        aq[ks] = *(const bf16x8*)(qb + (size_t)(m0 + lo) * QS_ + ks * 32 + hi * 8);

    f32x4 s[16] = {};
#pragma unroll
    for (int n0 = 0; n0 < 16; ++n0) {
        if (n0 <= n0hi) {
#pragma unroll
            for (int ks = 0; ks < 2; ++ks) {
                bf16x8 bk = *(const bf16x8*)(kb + (size_t)(n0 * 16 + lo) * QS_ + ks * 32 + hi * 8);
                s[n0] = __builtin_amdgcn_mfma_f32_16x16x32_bf16(aq[ks], bk, s[n0], 0, 0, 0);
            }
        }
    }

#pragma unroll
    for (int r = 0; r < 4; ++r) {
        const int qrow = m0 + hi * 4 + r;
        float mr = -1e30f;
#pragma unroll
        for (int n0 = 0; n0 < 16; ++n0) {
            if (n0 <= n0hi) {
                int key = n0 * 16 + lo;
                bool valid = (key < qrow) && (key < nt);
                float se = valid ? s[n0][r] * 0.125f : -1e30f;
                s[n0][r] = se;
                mr = fmaxf(mr, se);
            }
        }
#pragma unroll
        for (int off = 1; off < 16; off <<= 1) mr = fmaxf(mr, __shfl_xor(mr, off, 64));

        float lr = 0.f;
#pragma unroll
        for (int n0 = 0; n0 < 16; ++n0) {
            if (n0 <= n0hi) {
                float se = s[n0][r];
                float pv = (se > -5e29f) ? __expf(se - mr) : 0.f;
                s[n0][r] = pv;
                lr += pv;
            }
        }
#pragma unroll
        for (int off = 1; off < 16; off <<= 1) lr += __shfl_xor(lr, off, 64);

        float inv = (lr > 0.f) ? (1.f / lr) : 0.f;
#pragma unroll
        for (int n0 = 0; n0 < 16; ++n0) {
            if (n0 <= n0hi) {
                Plds[wave][(hi * 4 + r) * 264 + n0 * 16 + lo] = f2bf(s[n0][r] * inv);
            }
        }
    }

    f32x4 o[4] = {};
#pragma unroll
    for (int ks = 0; ks < 8; ++ks) {
        if (ks < nks) {
            const unsigned short* lp = &Plds[wave][lo * 264 + ks * 32 + hi * 8];
            bf16x8 ap = __builtin_bit_cast(bf16x8, *(const uint4*)lp);
#pragma unroll
            for (int nd = 0; nd < 4; ++nd) {
                const unsigned short* vp = vb + (size_t)(ks * 32 + hi * 8) * QS_ + nd * 16 + lo;
                u16x8 bu;
#pragma unroll
                for (int j = 0; j < 8; ++j) bu[j] = vp[(size_t)j * QS_];
                bf16x8 bvf = __builtin_bit_cast(bf16x8, bu);
                o[nd] = __builtin_amdgcn_mfma_f32_16x16x32_bf16(ap, bvf, o[nd], 0, 0, 0);
            }
        }
    }

#pragma unroll
    for (int nd = 0; nd < 4; ++nd) {
#pragma unroll
        for (int r = 0; r < 4; ++r) {
            ctx[((size_t)(b * T_ + m0 + hi * 4 + r)) * D_ + h * DH_ + nd * 16 + lo]
                = f2bf(o[nd][r]);
        }
    }
}

// ---------------------------------------------------------------------------
// Logits: one 256-thread block per (b,t) row. f32 H + f32 c.
// ---------------------------------------------------------------------------
__global__ __launch_bounds__(256) void logits_kernel(
    const float* __restrict__ H, const float* __restrict__ c,
    const float* __restrict__ Wc, const float* __restrict__ bc,
    const int* __restrict__ num_turns, float* __restrict__ out)
{
    __shared__ float sWc[2 * D_ * C_];
    __shared__ float sred[4 * C_];

    const int row = blockIdx.x;
    const int tid = threadIdx.x;

    for (int i = tid; i < 2 * D_ * C_; i += 256) sWc[i] = Wc[i];
    __syncthreads();

    const float* hrow = H + (size_t)row * D_;
    const float* crow = c + (size_t)row * D_;

    float accj[C_];
#pragma unroll
    for (int j = 0; j < C_; ++j) accj[j] = 0.f;

    for (int kk = tid; kk < D_; kk += 256) {
        float z = hrow[kk];
        const float* w = &sWc[kk * C_];
#pragma unroll
        for (int j = 0; j < C_; ++j) accj[j] += z * w[j];
    }
    for (int kk = tid; kk < D_; kk += 256) {
        float z = crow[kk];
        const float* w = &sWc[(D_ + kk) * C_];
#pragma unroll
        for (int j = 0; j < C_; ++j) accj[j] += z * w[j];
    }

#pragma unroll
    for (int off = 32; off; off >>= 1)
#pragma unroll
        for (int j = 0; j < C_; ++j) accj[j] += __shfl_xor(accj[j], off, 64);

    const int wave = tid >> 6;
    const int lane = tid & 63;
    if (lane == 0) {
#pragma unroll
        for (int j = 0; j < C_; ++j) sred[wave * C_ + j] = accj[j];
    }
    __syncthreads();

    if (tid < C_) {
        float tot = sred[tid] + sred[C_ + tid] + sred[2 * C_ + tid] + sred[3 * C_ + tid]
                  + bc[tid];
        out[(size_t)row * C_ + tid] = tot;
        int b = row >> 8;
        int t = row & (T_ - 1);
        if (t == num_turns[b] - 1) {
            out[(size_t)B_ * T_ * C_ + (size_t)b * C_ + tid] = tot;
        }
    }
}

// ---------------------------------------------------------------------------
extern "C" void kernel_launch(void* const* d_in, const int* in_sizes, int n_in,
                              void* d_out, int out_size, void* d_ws, size_t ws_size,
                              hipStream_t stream)
{
    const float* H  = (const float*)d_in[0];
    const float* Wq = (const float*)d_in[1];
    const float* bq = (const float*)d_in[2];
    const float* Wk = (const float*)d_in[3];
    const float* bk = (const float*)d_in[4];
    const float* Wv = (const float*)d_in[5];
    const float* bv = (const float*)d_in[6];
    const float* Wo = (const float*)d_in[7];
    const float* bo = (const float*)d_in[8];
    const float* Wc = (const float*)d_in[9];
    const float* bc = (const float*)d_in[10];
    const int* num_turns = (const int*)d_in[11];
    float* out = (float*)d_out;

    const int M = B_ * T_;                       // 16384
    const size_t per = (size_t)M * D_;           // 12,582,912
    const size_t wsz = (size_t)D_ * D_;          // 589,824

    unsigned short* ws16 = (unsigned short*)d_ws;
    unsigned short* Hb    = ws16;                         // per
    unsigned short* Wqkvt = Hb + per;                     // 3*wsz ([2304,768])
    unsigned short* Wot   = Wqkvt + 3 * wsz;              // wsz
    unsigned short* qkvb  = Wot + wsz;                    // M*2304
    unsigned short* ctxb  = qkvb + (size_t)M * QS_;       // per
    float* cb   = (float*)(ctxb + per);                   // per f32
    float* bqkv = cb + per;                               // 2304 f32

    // --- one-off converts / transposes (all tiny) ---
    convert_f32_bf16<<<(int)(per / 2048), 256, 0, stream>>>(H, Hb, (int)per);
    dim3 tGrid(D_ / 32, D_ / 32);
    transpose_to_bf16<<<tGrid, 256, 0, stream>>>(Wq, Wqkvt,            D_, D_);
    transpose_to_bf16<<<tGrid, 256, 0, stream>>>(Wk, Wqkvt + wsz,      D_, D_);
    transpose_to_bf16<<<tGrid, 256, 0, stream>>>(Wv, Wqkvt + 2 * wsz,  D_, D_);
    transpose_to_bf16<<<tGrid, 256, 0, stream>>>(Wo, Wot,              D_, D_);
    concat_bias3<<<9, 256, 0, stream>>>(bq, bk, bv, bqkv);

    // --- fused qkv projection: [M,768] @ [768,2304] -> [M,2304] bf16 ---
    dim3 qkvGrid(QS_ / GBN, M / GBM);            // (18,128)
    gemm_bf16_mfma<<<qkvGrid, 256, 0, stream>>>(Hb, Wqkvt, bqkv, qkvb,
                                                M, QS_, D_, /*flags=*/2);

    // --- attention ---
    dim3 aGrid(B_ * NH_, T_ / 64);
    attn_fused<<<aGrid, 256, 0, stream>>>(qkvb, num_turns, ctxb);

    // --- out projection (f32 out, t==0 rows zeroed) ---
    dim3 oGrid(D_ / GBN, M / GBM);               // (6,128)
    gemm_bf16_mfma<<<oGrid, 256, 0, stream>>>(ctxb, Wot, bo, cb,
                                              M, D_, D_, /*flags=*/1);

    // --- fused concat + logits + final gather ---
    logits_kernel<<<M, 256, 0, stream>>>(H, cb, Wc, bc, num_turns, out);
}

// Round 4
// 383.699 us; speedup vs baseline: 7.5514x; 1.1801x over previous
//
#include <hip/hip_runtime.h>
#include <hip/hip_bf16.h>

#define B_  64
#define T_  256
#define D_  768
#define NH_ 12
#define DH_ 64
#define C_  7
#define QS_ 2304            // qkv fused row stride (3*D)

using f32x4  = __attribute__((ext_vector_type(4))) float;
using bf16x8 = __attribute__((ext_vector_type(8))) __bf16;
using u16x8  = __attribute__((ext_vector_type(8))) unsigned short;

static __device__ inline unsigned short f2bf(float f) {
    union { float f; unsigned u; } c; c.f = f;
    unsigned u = c.u;
    return (unsigned short)((u + 0x7fffu + ((u >> 16) & 1u)) >> 16);
}

// async global->LDS, 16 bytes per lane (wave-uniform LDS base + lane*16)
#define ASYNC16(gp, lp) __builtin_amdgcn_global_load_lds(                      \
    (const __attribute__((address_space(1))) unsigned int*)(gp),               \
    (__attribute__((address_space(3))) unsigned int*)(lp), 16, 0, 0)

// ---------------------------------------------------------------------------
// f32 -> bf16 convert (n multiple of 8)
// ---------------------------------------------------------------------------
__global__ __launch_bounds__(256) void convert_f32_bf16(
    const float* __restrict__ in, unsigned short* __restrict__ out, int n)
{
    int i = (blockIdx.x * 256 + threadIdx.x) * 8;
    if (i < n) {
        float4 f0 = *(const float4*)(in + i);
        float4 f1 = *(const float4*)(in + i + 4);
        u16x8 u;
        u[0] = f2bf(f0.x); u[1] = f2bf(f0.y); u[2] = f2bf(f0.z); u[3] = f2bf(f0.w);
        u[4] = f2bf(f1.x); u[5] = f2bf(f1.y); u[6] = f2bf(f1.z); u[7] = f2bf(f1.w);
        *(uint4*)(out + i) = __builtin_bit_cast(uint4, u);
    }
}

// ---------------------------------------------------------------------------
// W [K,N] f32 -> Wt [N,K] bf16 (transpose), 32x32 LDS tiles
// ---------------------------------------------------------------------------
__global__ __launch_bounds__(256) void transpose_to_bf16(
    const float* __restrict__ W, unsigned short* __restrict__ Wt, int rows, int cols)
{
    __shared__ float tile[32][33];
    const int bx = blockIdx.x * 32;
    const int by = blockIdx.y * 32;
    const int tx = threadIdx.x & 31;
    const int ty = threadIdx.x >> 5;
#pragma unroll
    for (int i = ty; i < 32; i += 8)
        tile[i][tx] = W[(size_t)(by + i) * cols + bx + tx];
    __syncthreads();
#pragma unroll
    for (int i = ty; i < 32; i += 8)
        Wt[(size_t)(bx + i) * rows + by + tx] = f2bf(tile[tx][i]);
}

__global__ __launch_bounds__(256) void concat_bias3(
    const float* __restrict__ b0, const float* __restrict__ b1,
    const float* __restrict__ b2, float* __restrict__ out)
{
    int i = blockIdx.x * 256 + threadIdx.x;
    if (i < D_)          out[i] = b0[i];
    else if (i < 2 * D_) out[i] = b1[i - D_];
    else if (i < 3 * D_) out[i] = b2[i - 2 * D_];
}

// ---------------------------------------------------------------------------
// bf16 MFMA GEMM (m97 structure): C[M,N] = A[M,K] @ Bt[N,K]^T + bias
// flags: 1 = zero t==0 rows, 2 = bf16 output (else f32).
// ---------------------------------------------------------------------------
#define GBM 128
#define GBN 128
#define GBK 32

__global__ __launch_bounds__(256) void gemm_bf16_mfma(
    const unsigned short* __restrict__ A,
    const unsigned short* __restrict__ Bt,
    const float* __restrict__ bias,
    void* __restrict__ Cout,
    int M, int N, int K, int flags)
{
    __shared__ unsigned short As[GBM * GBK];
    __shared__ unsigned short Bs[GBN * GBK];

    const int tid = threadIdx.x;
    const int wv  = tid >> 6;
    const int ln  = tid & 63;
    const int hi  = ln >> 4;
    const int lo  = ln & 15;

    const int row0 = blockIdx.y * GBM;
    const int col0 = blockIdx.x * GBN;
    const int wm = (wv & 1) * 64;
    const int wn = (wv >> 1) * 64;

    f32x4 acc[4][4] = {};

    const int r0a = (0 * 256 + tid) >> 2, kc0 = (0 * 256 + tid) & 3;
    const int r1a = (1 * 256 + tid) >> 2, kc1 = (1 * 256 + tid) & 3;

    for (int k0 = 0; k0 < K; k0 += GBK) {
        ASYNC16(A + (size_t)(row0 + r0a) * K + k0 + kc0 * 8, &As[(0 * 256 + wv * 64) * 8]);
        ASYNC16(A + (size_t)(row0 + r1a) * K + k0 + kc1 * 8, &As[(1 * 256 + wv * 64) * 8]);
        ASYNC16(Bt + (size_t)(col0 + r0a) * K + k0 + kc0 * 8, &Bs[(0 * 256 + wv * 64) * 8]);
        ASYNC16(Bt + (size_t)(col0 + r1a) * K + k0 + kc1 * 8, &Bs[(1 * 256 + wv * 64) * 8]);
        __syncthreads();

        bf16x8 af[4], bf[4];
#pragma unroll
        for (int i = 0; i < 4; ++i)
            af[i] = *(const bf16x8*)&As[(wm + i * 16 + lo) * GBK + hi * 8];
#pragma unroll
        for (int j = 0; j < 4; ++j)
            bf[j] = *(const bf16x8*)&Bs[(wn + j * 16 + lo) * GBK + hi * 8];
#pragma unroll
        for (int i = 0; i < 4; ++i)
#pragma unroll
            for (int j = 0; j < 4; ++j)
                acc[i][j] = __builtin_amdgcn_mfma_f32_16x16x32_bf16(af[i], bf[j], acc[i][j], 0, 0, 0);
        __syncthreads();
    }

    const bool zt  = (flags & 1) != 0;
    const bool obf = (flags & 2) != 0;
#pragma unroll
    for (int j = 0; j < 4; ++j) {
        const int col = col0 + wn + j * 16 + lo;
        const float bcol = bias[col];
#pragma unroll
        for (int i = 0; i < 4; ++i) {
#pragma unroll
            for (int r = 0; r < 4; ++r) {
                const int row = row0 + wm + i * 16 + hi * 4 + r;
                float val = acc[i][j][r] + bcol;
                if (zt && ((row & (T_ - 1)) == 0)) val = 0.f;
                if (obf) ((unsigned short*)Cout)[(size_t)row * N + col] = f2bf(val);
                else     ((float*)Cout)[(size_t)row * N + col] = val;
            }
        }
    }
}

// ---------------------------------------------------------------------------
// Fused MFMA flash attention over the packed bf16 qkv buffer [M, 2304].
// ---------------------------------------------------------------------------
__global__ __launch_bounds__(256) void attn_fused(
    const unsigned short* __restrict__ qkv, const int* __restrict__ num_turns,
    unsigned short* __restrict__ ctx)
{
    __shared__ unsigned short Plds[4][16 * 264];

    const int bh = blockIdx.x;
    const int b = bh / NH_;
    const int h = bh - b * NH_;
    const int qt = blockIdx.y;
    const int tid = threadIdx.x;
    const int wave = tid >> 6;
    const int lane = tid & 63;
    const int hi = lane >> 4;
    const int lo = lane & 15;

    const int m0 = qt * 64 + wave * 16;
    const int nt = num_turns[b];

    const int kmax = min(m0 + 14, nt - 1);
    const int n0hi = (kmax >> 4) | 1;
    const int nks  = (kmax >> 5) + 1;

    const unsigned short* qb = qkv + (size_t)(b * T_) * QS_ + h * DH_;
    const unsigned short* kb = qb + D_;
    const unsigned short* vb = qb + 2 * D_;

    bf16x8 aq[2];
#pragma unroll
    for (int ks = 0; ks < 2; ++ks)
        aq[ks] = *(const bf16x8*)(qb + (size_t)(m0 + lo) * QS_ + ks * 32 + hi * 8);

    f32x4 s[16] = {};
#pragma unroll
    for (int n0 = 0; n0 < 16; ++n0) {
        if (n0 <= n0hi) {
#pragma unroll
            for (int ks = 0; ks < 2; ++ks) {
                bf16x8 bk = *(const bf16x8*)(kb + (size_t)(n0 * 16 + lo) * QS_ + ks * 32 + hi * 8);
                s[n0] = __builtin_amdgcn_mfma_f32_16x16x32_bf16(aq[ks], bk, s[n0], 0, 0, 0);
            }
        }
    }

#pragma unroll
    for (int r = 0; r < 4; ++r) {
        const int qrow = m0 + hi * 4 + r;
        float mr = -1e30f;
#pragma unroll
        for (int n0 = 0; n0 < 16; ++n0) {
            if (n0 <= n0hi) {
                int key = n0 * 16 + lo;
                bool valid = (key < qrow) && (key < nt);
                float se = valid ? s[n0][r] * 0.125f : -1e30f;
                s[n0][r] = se;
                mr = fmaxf(mr, se);
            }
        }
#pragma unroll
        for (int off = 1; off < 16; off <<= 1) mr = fmaxf(mr, __shfl_xor(mr, off, 64));

        float lr = 0.f;
#pragma unroll
        for (int n0 = 0; n0 < 16; ++n0) {
            if (n0 <= n0hi) {
                float se = s[n0][r];
                float pv = (se > -5e29f) ? __expf(se - mr) : 0.f;
                s[n0][r] = pv;
                lr += pv;
            }
        }
#pragma unroll
        for (int off = 1; off < 16; off <<= 1) lr += __shfl_xor(lr, off, 64);

        float inv = (lr > 0.f) ? (1.f / lr) : 0.f;
#pragma unroll
        for (int n0 = 0; n0 < 16; ++n0) {
            if (n0 <= n0hi) {
                Plds[wave][(hi * 4 + r) * 264 + n0 * 16 + lo] = f2bf(s[n0][r] * inv);
            }
        }
    }

    f32x4 o[4] = {};
#pragma unroll
    for (int ks = 0; ks < 8; ++ks) {
        if (ks < nks) {
            const unsigned short* lp = &Plds[wave][lo * 264 + ks * 32 + hi * 8];
            bf16x8 ap = __builtin_bit_cast(bf16x8, *(const uint4*)lp);
#pragma unroll
            for (int nd = 0; nd < 4; ++nd) {
                const unsigned short* vp = vb + (size_t)(ks * 32 + hi * 8) * QS_ + nd * 16 + lo;
                u16x8 bu;
#pragma unroll
                for (int j = 0; j < 8; ++j) bu[j] = vp[(size_t)j * QS_];
                bf16x8 bvf = __builtin_bit_cast(bf16x8, bu);
                o[nd] = __builtin_amdgcn_mfma_f32_16x16x32_bf16(ap, bvf, o[nd], 0, 0, 0);
            }
        }
    }

#pragma unroll
    for (int nd = 0; nd < 4; ++nd) {
#pragma unroll
        for (int r = 0; r < 4; ++r) {
            ctx[((size_t)(b * T_ + m0 + hi * 4 + r)) * D_ + h * DH_ + nd * 16 + lo]
                = f2bf(o[nd][r]);
        }
    }
}

// ---------------------------------------------------------------------------
// Logits as skinny MFMA GEMM: M=16384, N=16 (7 used), K=1536 (Hb | cb16).
// 256 blocks x 4 waves; wave owns 16 rows. WcT staged once per block in LDS
// as bf16 [16][1536] padded to row stride 1544 (16B-aligned b128 reads).
// ---------------------------------------------------------------------------
#define WCP 1544

__global__ __launch_bounds__(256) void logits_mfma(
    const unsigned short* __restrict__ Hb, const unsigned short* __restrict__ cb,
    const float* __restrict__ Wc, const float* __restrict__ bc,
    const int* __restrict__ num_turns, float* __restrict__ out)
{
    __shared__ unsigned short sW[16 * WCP];   // 49408 B

    const int tid = threadIdx.x;
    const int wave = tid >> 6;
    const int lane = tid & 63;
    const int hi = lane >> 4;
    const int lo = lane & 15;

    // stage WcT: sW[n][k] = Wc[k*7+n] (n<7) else 0, as bf16
    for (int i = tid; i < 16 * 1536; i += 256) {
        int n = i & 15, kk = i >> 4;
        float val = (n < C_) ? Wc[(size_t)kk * C_ + n] : 0.f;
        sW[n * WCP + kk] = f2bf(val);
    }
    __syncthreads();

    const int m0 = blockIdx.x * 64 + wave * 16;   // 16 rows per wave
    const unsigned short* hrow = Hb + (size_t)(m0 + lo) * D_;
    const unsigned short* crow = cb + (size_t)(m0 + lo) * D_;

    f32x4 acc = {};
#pragma unroll
    for (int kt = 0; kt < 24; ++kt) {
        bf16x8 a = *(const bf16x8*)(hrow + kt * 32 + hi * 8);
        bf16x8 w = *(const bf16x8*)&sW[lo * WCP + kt * 32 + hi * 8];
        acc = __builtin_amdgcn_mfma_f32_16x16x32_bf16(a, w, acc, 0, 0, 0);
    }
#pragma unroll
    for (int kt = 0; kt < 24; ++kt) {
        bf16x8 a = *(const bf16x8*)(crow + kt * 32 + hi * 8);
        bf16x8 w = *(const bf16x8*)&sW[lo * WCP + (768 + kt * 32) + hi * 8];
        acc = __builtin_amdgcn_mfma_f32_16x16x32_bf16(a, w, acc, 0, 0, 0);
    }

    // C-layout: col=lo (logit index), row=m0+hi*4+r
    if (lo < C_) {
        const float bias = bc[lo];
#pragma unroll
        for (int r = 0; r < 4; ++r) {
            const int row = m0 + hi * 4 + r;
            const float tot = acc[r] + bias;
            out[(size_t)row * C_ + lo] = tot;
            const int b = row >> 8;
            const int t = row & (T_ - 1);
            if (t == num_turns[b] - 1)
                out[(size_t)B_ * T_ * C_ + (size_t)b * C_ + lo] = tot;
        }
    }
}

// ---------------------------------------------------------------------------
extern "C" void kernel_launch(void* const* d_in, const int* in_sizes, int n_in,
                              void* d_out, int out_size, void* d_ws, size_t ws_size,
                              hipStream_t stream)
{
    const float* H  = (const float*)d_in[0];
    const float* Wq = (const float*)d_in[1];
    const float* bq = (const float*)d_in[2];
    const float* Wk = (const float*)d_in[3];
    const float* bk = (const float*)d_in[4];
    const float* Wv = (const float*)d_in[5];
    const float* bv = (const float*)d_in[6];
    const float* Wo = (const float*)d_in[7];
    const float* bo = (const float*)d_in[8];
    const float* Wc = (const float*)d_in[9];
    const float* bc = (const float*)d_in[10];
    const int* num_turns = (const int*)d_in[11];
    float* out = (float*)d_out;

    const int M = B_ * T_;                       // 16384
    const size_t per = (size_t)M * D_;           // 12,582,912
    const size_t wsz = (size_t)D_ * D_;

    unsigned short* ws16 = (unsigned short*)d_ws;
    unsigned short* Hb    = ws16;                         // per
    unsigned short* Wqkvt = Hb + per;                     // 3*wsz
    unsigned short* Wot   = Wqkvt + 3 * wsz;              // wsz
    unsigned short* qkvb  = Wot + wsz;                    // M*2304
    unsigned short* ctxb  = qkvb + (size_t)M * QS_;       // per
    unsigned short* cb16  = ctxb + per;                   // per (bf16 now)
    float* bqkv = (float*)(cb16 + per);                   // 2304 f32

    convert_f32_bf16<<<(int)(per / 2048), 256, 0, stream>>>(H, Hb, (int)per);
    dim3 tGrid(D_ / 32, D_ / 32);
    transpose_to_bf16<<<tGrid, 256, 0, stream>>>(Wq, Wqkvt,            D_, D_);
    transpose_to_bf16<<<tGrid, 256, 0, stream>>>(Wk, Wqkvt + wsz,      D_, D_);
    transpose_to_bf16<<<tGrid, 256, 0, stream>>>(Wv, Wqkvt + 2 * wsz,  D_, D_);
    transpose_to_bf16<<<tGrid, 256, 0, stream>>>(Wo, Wot,              D_, D_);
    concat_bias3<<<9, 256, 0, stream>>>(bq, bk, bv, bqkv);

    dim3 qkvGrid(QS_ / GBN, M / GBM);            // (18,128)
    gemm_bf16_mfma<<<qkvGrid, 256, 0, stream>>>(Hb, Wqkvt, bqkv, qkvb,
                                                M, QS_, D_, /*flags=*/2);

    dim3 aGrid(B_ * NH_, T_ / 64);
    attn_fused<<<aGrid, 256, 0, stream>>>(qkvb, num_turns, ctxb);

    // out projection -> bf16 c, t==0 rows zeroed
    dim3 oGrid(D_ / GBN, M / GBM);               // (6,128)
    gemm_bf16_mfma<<<oGrid, 256, 0, stream>>>(ctxb, Wot, bo, cb16,
                                              M, D_, D_, /*flags=*/3);

    // logits skinny GEMM + final gather
    logits_mfma<<<M / 64, 256, 0, stream>>>(Hb, cb16, Wc, bc, num_turns, out);
}

// Round 5
// 367.388 us; speedup vs baseline: 7.8866x; 1.0444x over previous
//
#include <hip/hip_runtime.h>
#include <hip/hip_bf16.h>

#define B_  64
#define T_  256
#define D_  768
#define NH_ 12
#define DH_ 64
#define C_  7
#define QS_ 2304            // qkv fused row stride (3*D)

using f32x4  = __attribute__((ext_vector_type(4))) float;
using bf16x8 = __attribute__((ext_vector_type(8))) __bf16;
using u16x8  = __attribute__((ext_vector_type(8))) unsigned short;

static __device__ inline unsigned short f2bf(float f) {
    union { float f; unsigned u; } c; c.f = f;
    unsigned u = c.u;
    return (unsigned short)((u + 0x7fffu + ((u >> 16) & 1u)) >> 16);
}

// async global->LDS, 16 bytes per lane (wave-uniform LDS base + lane*16)
#define ASYNC16(gp, lp) __builtin_amdgcn_global_load_lds(                      \
    (const __attribute__((address_space(1))) unsigned int*)(gp),               \
    (__attribute__((address_space(3))) unsigned int*)(lp), 16, 0, 0)

// ---------------------------------------------------------------------------
// f32 -> bf16 convert (n multiple of 8)
// ---------------------------------------------------------------------------
__global__ __launch_bounds__(256) void convert_f32_bf16(
    const float* __restrict__ in, unsigned short* __restrict__ out, int n)
{
    int i = (blockIdx.x * 256 + threadIdx.x) * 8;
    if (i < n) {
        float4 f0 = *(const float4*)(in + i);
        float4 f1 = *(const float4*)(in + i + 4);
        u16x8 u;
        u[0] = f2bf(f0.x); u[1] = f2bf(f0.y); u[2] = f2bf(f0.z); u[3] = f2bf(f0.w);
        u[4] = f2bf(f1.x); u[5] = f2bf(f1.y); u[6] = f2bf(f1.z); u[7] = f2bf(f1.w);
        *(uint4*)(out + i) = __builtin_bit_cast(uint4, u);
    }
}

// ---------------------------------------------------------------------------
// Batched: 4x (W [768,768] f32 -> Wt [768,768] bf16 transpose), z picks matrix
// ---------------------------------------------------------------------------
__global__ __launch_bounds__(256) void transpose4_to_bf16(
    const float* __restrict__ s0, const float* __restrict__ s1,
    const float* __restrict__ s2, const float* __restrict__ s3,
    unsigned short* __restrict__ d0, unsigned short* __restrict__ d1,
    unsigned short* __restrict__ d2, unsigned short* __restrict__ d3)
{
    __shared__ float tile[32][33];
    const float* W; unsigned short* Wt;
    switch (blockIdx.z) {
        case 0:  W = s0; Wt = d0; break;
        case 1:  W = s1; Wt = d1; break;
        case 2:  W = s2; Wt = d2; break;
        default: W = s3; Wt = d3; break;
    }
    const int bx = blockIdx.x * 32;
    const int by = blockIdx.y * 32;
    const int tx = threadIdx.x & 31;
    const int ty = threadIdx.x >> 5;
#pragma unroll
    for (int i = ty; i < 32; i += 8)
        tile[i][tx] = W[(size_t)(by + i) * D_ + bx + tx];
    __syncthreads();
#pragma unroll
    for (int i = ty; i < 32; i += 8)
        Wt[(size_t)(bx + i) * D_ + by + tx] = f2bf(tile[tx][i]);
}

__global__ __launch_bounds__(256) void concat_bias3(
    const float* __restrict__ b0, const float* __restrict__ b1,
    const float* __restrict__ b2, float* __restrict__ out)
{
    int i = blockIdx.x * 256 + threadIdx.x;
    if (i < D_)          out[i] = b0[i];
    else if (i < 2 * D_) out[i] = b1[i - D_];
    else if (i < 3 * D_) out[i] = b2[i - 2 * D_];
}

// ---------------------------------------------------------------------------
// bf16 MFMA GEMM (m97 structure): C[M,N] = A[M,K] @ Bt[N,K]^T + bias
// flags: 1 = zero t==0 rows, 2 = bf16 output (else f32).
// XCD-aware remap: xcd = L%8 owns a contiguous (gridDim.y/8)-tile M-band and
// sweeps N fastest -> A band (3.1 MB) + B cycle stay in the XCD's 4 MiB L2.
// Requires gridDim.y % 8 == 0 (both call sites use y=128).
// ---------------------------------------------------------------------------
#define GBM 128
#define GBN 128
#define GBK 32

__global__ __launch_bounds__(256) void gemm_bf16_mfma(
    const unsigned short* __restrict__ A,
    const unsigned short* __restrict__ Bt,
    const float* __restrict__ bias,
    void* __restrict__ Cout,
    int M, int N, int K, int flags)
{
    __shared__ unsigned short As[GBM * GBK];
    __shared__ unsigned short Bs[GBN * GBK];

    const int tid = threadIdx.x;
    const int wv  = tid >> 6;
    const int ln  = tid & 63;
    const int hi  = ln >> 4;
    const int lo  = ln & 15;

    // XCD swizzle
    const int L   = blockIdx.y * gridDim.x + blockIdx.x;
    const int xcd = L & 7;
    const int li  = L >> 3;
    const int my  = xcd * (int)(gridDim.y >> 3) + li / (int)gridDim.x;
    const int nx  = li % (int)gridDim.x;

    const int row0 = my * GBM;
    const int col0 = nx * GBN;
    const int wm = (wv & 1) * 64;
    const int wn = (wv >> 1) * 64;

    f32x4 acc[4][4] = {};

    const int r0a = (0 * 256 + tid) >> 2, kc0 = (0 * 256 + tid) & 3;
    const int r1a = (1 * 256 + tid) >> 2, kc1 = (1 * 256 + tid) & 3;

    for (int k0 = 0; k0 < K; k0 += GBK) {
        ASYNC16(A + (size_t)(row0 + r0a) * K + k0 + kc0 * 8, &As[(0 * 256 + wv * 64) * 8]);
        ASYNC16(A + (size_t)(row0 + r1a) * K + k0 + kc1 * 8, &As[(1 * 256 + wv * 64) * 8]);
        ASYNC16(Bt + (size_t)(col0 + r0a) * K + k0 + kc0 * 8, &Bs[(0 * 256 + wv * 64) * 8]);
        ASYNC16(Bt + (size_t)(col0 + r1a) * K + k0 + kc1 * 8, &Bs[(1 * 256 + wv * 64) * 8]);
        __syncthreads();

        bf16x8 af[4], bf[4];
#pragma unroll
        for (int i = 0; i < 4; ++i)
            af[i] = *(const bf16x8*)&As[(wm + i * 16 + lo) * GBK + hi * 8];
#pragma unroll
        for (int j = 0; j < 4; ++j)
            bf[j] = *(const bf16x8*)&Bs[(wn + j * 16 + lo) * GBK + hi * 8];
#pragma unroll
        for (int i = 0; i < 4; ++i)
#pragma unroll
            for (int j = 0; j < 4; ++j)
                acc[i][j] = __builtin_amdgcn_mfma_f32_16x16x32_bf16(af[i], bf[j], acc[i][j], 0, 0, 0);
        __syncthreads();
    }

    const bool zt  = (flags & 1) != 0;
    const bool obf = (flags & 2) != 0;
#pragma unroll
    for (int j = 0; j < 4; ++j) {
        const int col = col0 + wn + j * 16 + lo;
        const float bcol = bias[col];
#pragma unroll
        for (int i = 0; i < 4; ++i) {
#pragma unroll
            for (int r = 0; r < 4; ++r) {
                const int row = row0 + wm + i * 16 + hi * 4 + r;
                float val = acc[i][j][r] + bcol;
                if (zt && ((row & (T_ - 1)) == 0)) val = 0.f;
                if (obf) ((unsigned short*)Cout)[(size_t)row * N + col] = f2bf(val);
                else     ((float*)Cout)[(size_t)row * N + col] = val;
            }
        }
    }
}

// ---------------------------------------------------------------------------
// Fused MFMA flash attention over the packed bf16 qkv buffer [M, 2304].
// ---------------------------------------------------------------------------
__global__ __launch_bounds__(256) void attn_fused(
    const unsigned short* __restrict__ qkv, const int* __restrict__ num_turns,
    unsigned short* __restrict__ ctx)
{
    __shared__ unsigned short Plds[4][16 * 264];

    const int bh = blockIdx.x;
    const int b = bh / NH_;
    const int h = bh - b * NH_;
    const int qt = blockIdx.y;
    const int tid = threadIdx.x;
    const int wave = tid >> 6;
    const int lane = tid & 63;
    const int hi = lane >> 4;
    const int lo = lane & 15;

    const int m0 = qt * 64 + wave * 16;
    const int nt = num_turns[b];

    const int kmax = min(m0 + 14, nt - 1);
    const int n0hi = (kmax >> 4) | 1;
    const int nks  = (kmax >> 5) + 1;

    const unsigned short* qb = qkv + (size_t)(b * T_) * QS_ + h * DH_;
    const unsigned short* kb = qb + D_;
    const unsigned short* vb = qb + 2 * D_;

    bf16x8 aq[2];
#pragma unroll
    for (int ks = 0; ks < 2; ++ks)
        aq[ks] = *(const bf16x8*)(qb + (size_t)(m0 + lo) * QS_ + ks * 32 + hi * 8);

    f32x4 s[16] = {};
#pragma unroll
    for (int n0 = 0; n0 < 16; ++n0) {
        if (n0 <= n0hi) {
#pragma unroll
            for (int ks = 0; ks < 2; ++ks) {
                bf16x8 bk = *(const bf16x8*)(kb + (size_t)(n0 * 16 + lo) * QS_ + ks * 32 + hi * 8);
                s[n0] = __builtin_amdgcn_mfma_f32_16x16x32_bf16(aq[ks], bk, s[n0], 0, 0, 0);
            }
        }
    }

#pragma unroll
    for (int r = 0; r < 4; ++r) {
        const int qrow = m0 + hi * 4 + r;
        float mr = -1e30f;
#pragma unroll
        for (int n0 = 0; n0 < 16; ++n0) {
            if (n0 <= n0hi) {
                int key = n0 * 16 + lo;
                bool valid = (key < qrow) && (key < nt);
                float se = valid ? s[n0][r] * 0.125f : -1e30f;
                s[n0][r] = se;
                mr = fmaxf(mr, se);
            }
        }
#pragma unroll
        for (int off = 1; off < 16; off <<= 1) mr = fmaxf(mr, __shfl_xor(mr, off, 64));

        float lr = 0.f;
#pragma unroll
        for (int n0 = 0; n0 < 16; ++n0) {
            if (n0 <= n0hi) {
                float se = s[n0][r];
                float pv = (se > -5e29f) ? __expf(se - mr) : 0.f;
                s[n0][r] = pv;
                lr += pv;
            }
        }
#pragma unroll
        for (int off = 1; off < 16; off <<= 1) lr += __shfl_xor(lr, off, 64);

        float inv = (lr > 0.f) ? (1.f / lr) : 0.f;
#pragma unroll
        for (int n0 = 0; n0 < 16; ++n0) {
            if (n0 <= n0hi) {
                Plds[wave][(hi * 4 + r) * 264 + n0 * 16 + lo] = f2bf(s[n0][r] * inv);
            }
        }
    }

    f32x4 o[4] = {};
#pragma unroll
    for (int ks = 0; ks < 8; ++ks) {
        if (ks < nks) {
            const unsigned short* lp = &Plds[wave][lo * 264 + ks * 32 + hi * 8];
            bf16x8 ap = __builtin_bit_cast(bf16x8, *(const uint4*)lp);
#pragma unroll
            for (int nd = 0; nd < 4; ++nd) {
                const unsigned short* vp = vb + (size_t)(ks * 32 + hi * 8) * QS_ + nd * 16 + lo;
                u16x8 bu;
#pragma unroll
                for (int j = 0; j < 8; ++j) bu[j] = vp[(size_t)j * QS_];
                bf16x8 bvf = __builtin_bit_cast(bf16x8, bu);
                o[nd] = __builtin_amdgcn_mfma_f32_16x16x32_bf16(ap, bvf, o[nd], 0, 0, 0);
            }
        }
    }

#pragma unroll
    for (int nd = 0; nd < 4; ++nd) {
#pragma unroll
        for (int r = 0; r < 4; ++r) {
            ctx[((size_t)(b * T_ + m0 + hi * 4 + r)) * D_ + h * DH_ + nd * 16 + lo]
                = f2bf(o[nd][r]);
        }
    }
}

// ---------------------------------------------------------------------------
// Logits as skinny MFMA GEMM: M=16384, N=16 (7 used), K=1536 (Hb | cb16).
// ---------------------------------------------------------------------------
#define WCP 1544

__global__ __launch_bounds__(256) void logits_mfma(
    const unsigned short* __restrict__ Hb, const unsigned short* __restrict__ cb,
    const float* __restrict__ Wc, const float* __restrict__ bc,
    const int* __restrict__ num_turns, float* __restrict__ out)
{
    __shared__ unsigned short sW[16 * WCP];

    const int tid = threadIdx.x;
    const int wave = tid >> 6;
    const int lane = tid & 63;
    const int hi = lane >> 4;
    const int lo = lane & 15;

    for (int i = tid; i < 16 * 1536; i += 256) {
        int n = i & 15, kk = i >> 4;
        float val = (n < C_) ? Wc[(size_t)kk * C_ + n] : 0.f;
        sW[n * WCP + kk] = f2bf(val);
    }
    __syncthreads();

    const int m0 = blockIdx.x * 64 + wave * 16;
    const unsigned short* hrow = Hb + (size_t)(m0 + lo) * D_;
    const unsigned short* crow = cb + (size_t)(m0 + lo) * D_;

    f32x4 acc = {};
#pragma unroll
    for (int kt = 0; kt < 24; ++kt) {
        bf16x8 a = *(const bf16x8*)(hrow + kt * 32 + hi * 8);
        bf16x8 w = *(const bf16x8*)&sW[lo * WCP + kt * 32 + hi * 8];
        acc = __builtin_amdgcn_mfma_f32_16x16x32_bf16(a, w, acc, 0, 0, 0);
    }
#pragma unroll
    for (int kt = 0; kt < 24; ++kt) {
        bf16x8 a = *(const bf16x8*)(crow + kt * 32 + hi * 8);
        bf16x8 w = *(const bf16x8*)&sW[lo * WCP + (768 + kt * 32) + hi * 8];
        acc = __builtin_amdgcn_mfma_f32_16x16x32_bf16(a, w, acc, 0, 0, 0);
    }

    if (lo < C_) {
        const float bias = bc[lo];
#pragma unroll
        for (int r = 0; r < 4; ++r) {
            const int row = m0 + hi * 4 + r;
            const float tot = acc[r] + bias;
            out[(size_t)row * C_ + lo] = tot;
            const int b = row >> 8;
            const int t = row & (T_ - 1);
            if (t == num_turns[b] - 1)
                out[(size_t)B_ * T_ * C_ + (size_t)b * C_ + lo] = tot;
        }
    }
}

// ---------------------------------------------------------------------------
extern "C" void kernel_launch(void* const* d_in, const int* in_sizes, int n_in,
                              void* d_out, int out_size, void* d_ws, size_t ws_size,
                              hipStream_t stream)
{
    const float* H  = (const float*)d_in[0];
    const float* Wq = (const float*)d_in[1];
    const float* bq = (const float*)d_in[2];
    const float* Wk = (const float*)d_in[3];
    const float* bk = (const float*)d_in[4];
    const float* Wv = (const float*)d_in[5];
    const float* bv = (const float*)d_in[6];
    const float* Wo = (const float*)d_in[7];
    const float* bo = (const float*)d_in[8];
    const float* Wc = (const float*)d_in[9];
    const float* bc = (const float*)d_in[10];
    const int* num_turns = (const int*)d_in[11];
    float* out = (float*)d_out;

    const int M = B_ * T_;                       // 16384
    const size_t per = (size_t)M * D_;           // 12,582,912
    const size_t wsz = (size_t)D_ * D_;

    unsigned short* ws16 = (unsigned short*)d_ws;
    unsigned short* Hb    = ws16;                         // per
    unsigned short* Wqkvt = Hb + per;                     // 3*wsz
    unsigned short* Wot   = Wqkvt + 3 * wsz;              // wsz
    unsigned short* qkvb  = Wot + wsz;                    // M*2304
    unsigned short* ctxb  = qkvb + (size_t)M * QS_;       // per
    unsigned short* cb16  = ctxb + per;                   // per
    float* bqkv = (float*)(cb16 + per);                   // 2304 f32

    convert_f32_bf16<<<(int)(per / 2048), 256, 0, stream>>>(H, Hb, (int)per);
    dim3 tGrid(D_ / 32, D_ / 32, 4);
    transpose4_to_bf16<<<tGrid, 256, 0, stream>>>(
        Wq, Wk, Wv, Wo,
        Wqkvt, Wqkvt + wsz, Wqkvt + 2 * wsz, Wot);
    concat_bias3<<<9, 256, 0, stream>>>(bq, bk, bv, bqkv);

    dim3 qkvGrid(QS_ / GBN, M / GBM);            // (18,128)
    gemm_bf16_mfma<<<qkvGrid, 256, 0, stream>>>(Hb, Wqkvt, bqkv, qkvb,
                                                M, QS_, D_, /*flags=*/2);

    dim3 aGrid(B_ * NH_, T_ / 64);
    attn_fused<<<aGrid, 256, 0, stream>>>(qkvb, num_turns, ctxb);

    dim3 oGrid(D_ / GBN, M / GBM);               // (6,128)
    gemm_bf16_mfma<<<oGrid, 256, 0, stream>>>(ctxb, Wot, bo, cb16,
                                              M, D_, D_, /*flags=*/3);

    logits_mfma<<<M / 64, 256, 0, stream>>>(Hb, cb16, Wc, bc, num_turns, out);
}